// Round 1
// baseline (370.541 us; speedup 1.0000x reference)
//
#include <hip/hip_runtime.h>
#include <cmath>

// ---------------------------------------------------------------------------
// T5 MHSA: x->(QKV proj, f16 MFMA GEMM) -> flash attn w/ T5 bias -> out proj
// All matmuls on v_mfma_f32_16x16x32_f16. fp16 intermediates, fp32 accum.
// ---------------------------------------------------------------------------

typedef _Float16 f16x8 __attribute__((ext_vector_type(8)));
typedef _Float16 f16x4 __attribute__((ext_vector_type(4)));
typedef float    f32x4 __attribute__((ext_vector_type(4)));

__device__ __forceinline__ void gl_lds16(const void* g, void* l) {
  __builtin_amdgcn_global_load_lds(
      (__attribute__((address_space(1))) void*)g,
      (__attribute__((address_space(3))) void*)l,
      16, 0, 0);
}

// -------------------------------- convert ---------------------------------
__global__ void cvt_kernel(const float* __restrict__ in,
                           _Float16* __restrict__ out, int n4) {
  int i = blockIdx.x * blockDim.x + threadIdx.x;
  if (i >= n4) return;
  float4 v = reinterpret_cast<const float4*>(in)[i];
  f16x4 o;
  o[0] = (_Float16)v.x; o[1] = (_Float16)v.y;
  o[2] = (_Float16)v.z; o[3] = (_Float16)v.w;
  reinterpret_cast<f16x4*>(out)[i] = o;
}

// --------------------------------- GEMM -----------------------------------
// C = A(MxK) * Bm(NxK)^T.  128x128 tile, BK=32, 4 waves (2x2 of 64x64).
// MODE 0: QKV projection epilogue (route q/k -> qkbuf[b,h,i,128], v -> vt[b,h,d,i])
// MODE 1: fp32 store with bias into outf (row stride N)
template <int MODE>
__global__ __launch_bounds__(256, 2) void gemm_kernel(
    const _Float16* __restrict__ A, const _Float16* __restrict__ Bm,
    int M, int N, int K,
    const float* __restrict__ bias_q, const float* __restrict__ bias_v,
    _Float16* __restrict__ qkbuf, _Float16* __restrict__ vtbuf,
    const float* __restrict__ bias_o, float* __restrict__ outf) {
  __shared__ __align__(16) _Float16 lds_a[128 * 32];
  __shared__ __align__(16) _Float16 lds_b[128 * 32];
  const int t = threadIdx.x;
  const int w = t >> 6;
  const int lane = t & 63;
  const int lq = lane & 15, lg = lane >> 4;
  const int wr = w >> 1, wc = w & 1;
  const int m0 = blockIdx.y * 128, n0 = blockIdx.x * 128;

  // staging: chunk c = it*256 + t -> row c>>2 of tile, 8-elem k-chunk c&3
  const _Float16* pA0 = A + (size_t)(m0 + (t >> 2)) * K + (t & 3) * 8;
  const _Float16* pA1 = pA0 + (size_t)64 * K;
  const _Float16* pB0 = Bm + (size_t)(n0 + (t >> 2)) * K + (t & 3) * 8;
  const _Float16* pB1 = pB0 + (size_t)64 * K;
  _Float16* la0 = &lds_a[(w * 64) * 8];
  _Float16* la1 = &lds_a[(256 + w * 64) * 8];
  _Float16* lb0 = &lds_b[(w * 64) * 8];
  _Float16* lb1 = &lds_b[(256 + w * 64) * 8];

  f32x4 acc[4][4];
#pragma unroll
  for (int mi = 0; mi < 4; ++mi)
#pragma unroll
    for (int ni = 0; ni < 4; ++ni) acc[mi][ni] = (f32x4){0.f, 0.f, 0.f, 0.f};

  for (int k0 = 0; k0 < K; k0 += 32) {
    __syncthreads();
    gl_lds16(pA0 + k0, la0);
    gl_lds16(pA1 + k0, la1);
    gl_lds16(pB0 + k0, lb0);
    gl_lds16(pB1 + k0, lb1);
    __syncthreads();
    f16x8 af[4], bfr[4];
#pragma unroll
    for (int mi = 0; mi < 4; ++mi)
      af[mi] = *(const f16x8*)&lds_a[(wr * 64 + mi * 16 + lq) * 32 + lg * 8];
#pragma unroll
    for (int ni = 0; ni < 4; ++ni)
      bfr[ni] = *(const f16x8*)&lds_b[(wc * 64 + ni * 16 + lq) * 32 + lg * 8];
#pragma unroll
    for (int mi = 0; mi < 4; ++mi)
#pragma unroll
      for (int ni = 0; ni < 4; ++ni)
        acc[mi][ni] = __builtin_amdgcn_mfma_f32_16x16x32_f16(
            af[mi], bfr[ni], acc[mi][ni], 0, 0, 0);
  }

  // epilogue: C[mg][ng], mg row = wr*64+mi*16+lg*4+r, ng col = wc*64+ni*16+lq
  if (MODE == 0) {
    const bool isqk = (n0 < 2048);  // tile-uniform (2048 % 128 == 0)
#pragma unroll
    for (int mi = 0; mi < 4; ++mi)
#pragma unroll
      for (int ni = 0; ni < 4; ++ni)
#pragma unroll
        for (int r = 0; r < 4; ++r) {
          const int mg = m0 + wr * 64 + mi * 16 + lg * 4 + r;
          const int ng = n0 + wc * 64 + ni * 16 + lq;
          const int bb = mg >> 10, ii = mg & 1023;
          float val = acc[mi][ni][r];
          if (isqk) {
            val += bias_q[ng];
            const int hh = ng >> 7, cc = ng & 127;
            qkbuf[((size_t)((bb * 16 + hh) * 1024 + ii)) * 128 + cc] =
                (_Float16)val;
          } else {
            const int nn = ng - 2048;
            val += bias_v[nn];
            const int hh = nn >> 6, dv = nn & 63;
            vtbuf[((size_t)((bb * 16 + hh) * 64 + dv)) * 1024 + ii] =
                (_Float16)val;
          }
        }
  } else {
#pragma unroll
    for (int mi = 0; mi < 4; ++mi)
#pragma unroll
      for (int ni = 0; ni < 4; ++ni)
#pragma unroll
        for (int r = 0; r < 4; ++r) {
          const int mg = m0 + wr * 64 + mi * 16 + lg * 4 + r;
          const int ng = n0 + wc * 64 + ni * 16 + lq;
          outf[(size_t)mg * N + ng] = acc[mi][ni][r] + bias_o[ng];
        }
  }
}

// ------------------------------- attention --------------------------------
// One block = 4 waves; wave w owns 16 q-rows of a 64-row q-tile of one (b,h).
// S^T = mfma(K_frag, Q^T_frag): lane holds S[q=lq][j=j0+lg*4+r] -> softmax
// stats lane-local; P repacked via 1KiB/wave LDS into A-frag for PV (K=32).
__global__ __launch_bounds__(256, 2) void attn_kernel(
    const _Float16* __restrict__ qk,  // [B*H][1024][128] (q | k)
    const _Float16* __restrict__ vt,  // [B*H][64][1024]  (V^T)
    const float* __restrict__ bias,   // [32][16]
    _Float16* __restrict__ ao) {      // [B][1024][H*64]
  __shared__ float tab[129];
  __shared__ __align__(16) _Float16 plds[4 * 512];
  const int t = threadIdx.x;
  const int bid = blockIdx.x;
  const int tile = bid & 15, bh = bid >> 4;
  const int h = bh & 15, b = bh >> 4;
  if (t < 129) {
    // exact numpy t5 bucket: n<=16 -> n ; else 16 + floor(ln(n-15)*15/ln(113))
    const int bucket =
        (t <= 16) ? t : 16 + (int)(log((double)(t - 15)) * 15.0 / log(113.0));
    tab[t] = bias[bucket * 16 + h];
  }
  __syncthreads();

  const int w = t >> 6, lane = t & 63;
  const int lq = lane & 15, lg = lane >> 4;
  const int q0 = tile * 64 + w * 16;
  const int qi = q0 + lq;
  const _Float16* qkb = qk + (size_t)bh * 1024 * 128;
  const _Float16* kb = qkb + 64;
  const _Float16* vtb = vt + (size_t)bh * 64 * 1024;
  _Float16* pl = &plds[w * 512];

  const f16x8 qf0 = *(const f16x8*)&qkb[qi * 128 + lg * 8];
  const f16x8 qf1 = *(const f16x8*)&qkb[qi * 128 + 32 + lg * 8];

  f32x4 oacc[4];
#pragma unroll
  for (int db = 0; db < 4; ++db) oacc[db] = (f32x4){0.f, 0.f, 0.f, 0.f};
  float m_run = -__builtin_inff();
  float l_run = 0.f;

  const int njt = (q0 + 47) >> 5;  // j-tiles of 32 covering j <= q0+15
  for (int jt = 0; jt < njt; ++jt) {
    const int j0 = jt * 32;
    f32x4 st0 = {0.f, 0.f, 0.f, 0.f}, st1 = {0.f, 0.f, 0.f, 0.f};
    {
      f16x8 kf;
      kf = *(const f16x8*)&kb[(j0 + lq) * 128 + lg * 8];
      st0 = __builtin_amdgcn_mfma_f32_16x16x32_f16(kf, qf0, st0, 0, 0, 0);
      kf = *(const f16x8*)&kb[(j0 + lq) * 128 + 32 + lg * 8];
      st0 = __builtin_amdgcn_mfma_f32_16x16x32_f16(kf, qf1, st0, 0, 0, 0);
      kf = *(const f16x8*)&kb[(j0 + 16 + lq) * 128 + lg * 8];
      st1 = __builtin_amdgcn_mfma_f32_16x16x32_f16(kf, qf0, st1, 0, 0, 0);
      kf = *(const f16x8*)&kb[(j0 + 16 + lq) * 128 + 32 + lg * 8];
      st1 = __builtin_amdgcn_mfma_f32_16x16x32_f16(kf, qf1, st1, 0, 0, 0);
    }
    // scores + causal mask + T5 bias; lane holds q=qi, j = j0+hh*16+lg*4+r
    float xs[8];
    float tmax = -__builtin_inff();
#pragma unroll
    for (int hh = 0; hh < 2; ++hh)
#pragma unroll
      for (int r = 0; r < 4; ++r) {
        const int jj = j0 + hh * 16 + lg * 4 + r;
        const int dd = qi - jj;
        const float sv = hh ? st1[r] : st0[r];
        const float xv = (dd < 0)
                             ? -__builtin_inff()
                             : fmaf(sv, 0.125f, tab[dd > 128 ? 128 : dd]);
        xs[hh * 4 + r] = xv;
        tmax = fmaxf(tmax, xv);
      }
    tmax = fmaxf(tmax, __shfl_xor(tmax, 16));
    tmax = fmaxf(tmax, __shfl_xor(tmax, 32));
    const float m_new = fmaxf(m_run, tmax);
    const float sf = __expf(m_run - m_new);
    m_run = m_new;
    float p[8];
    float tsum = 0.f;
#pragma unroll
    for (int e = 0; e < 8; ++e) {
      p[e] = __expf(xs[e] - m_new);
      tsum += p[e];
    }
    tsum += __shfl_xor(tsum, 16);
    tsum += __shfl_xor(tsum, 32);
    l_run = l_run * sf + tsum;
    // rescale O: oacc row = q-row (lg*4+r); stats live at lane q (0..15)
    float sfo[4];
#pragma unroll
    for (int r = 0; r < 4; ++r) sfo[r] = __shfl(sf, (lg << 2) + r);
#pragma unroll
    for (int db = 0; db < 4; ++db)
#pragma unroll
      for (int r = 0; r < 4; ++r) oacc[db][r] *= sfo[r];
    // repack P (q=lq, k=lg*4+r / 16+lg*4+r) -> A-frag (q=lq, k=lg*8+e)
    f16x4 ph0, ph1;
#pragma unroll
    for (int r = 0; r < 4; ++r) {
      ph0[r] = (_Float16)p[r];
      ph1[r] = (_Float16)p[4 + r];
    }
    *(f16x4*)&pl[lq * 32 + lg * 4] = ph0;
    *(f16x4*)&pl[lq * 32 + 16 + lg * 4] = ph1;
    asm volatile("s_waitcnt lgkmcnt(0)" ::: "memory");
    const f16x8 pa = *(const f16x8*)&pl[lq * 32 + lg * 8];
#pragma unroll
    for (int db = 0; db < 4; ++db) {
      const f16x8 vf =
          *(const f16x8*)&vtb[(db * 16 + lq) * 1024 + j0 + lg * 8];
      oacc[db] = __builtin_amdgcn_mfma_f32_16x16x32_f16(pa, vf, oacc[db], 0, 0, 0);
    }
  }

  float linv[4];
#pragma unroll
  for (int r = 0; r < 4; ++r) linv[r] = 1.0f / __shfl(l_run, (lg << 2) + r);
  _Float16* aob = ao + ((size_t)b * 1024) * 1024 + h * 64;
#pragma unroll
  for (int db = 0; db < 4; ++db)
#pragma unroll
    for (int r = 0; r < 4; ++r) {
      const int qrow = q0 + lg * 4 + r;
      const int d = db * 16 + lq;
      aob[(size_t)qrow * 1024 + d] = (_Float16)(oacc[db][r] * linv[r]);
    }
}

// -------------------------------- launch ----------------------------------
extern "C" void kernel_launch(void* const* d_in, const int* in_sizes, int n_in,
                              void* d_out, int out_size, void* d_ws,
                              size_t ws_size, hipStream_t stream) {
  const float* x = (const float*)d_in[0];
  const float* qk_w = (const float*)d_in[1];
  const float* qk_b = (const float*)d_in[2];
  const float* v_w = (const float*)d_in[3];
  const float* v_b = (const float*)d_in[4];
  const float* out_w = (const float*)d_in[5];
  const float* out_b = (const float*)d_in[6];
  const float* bias = (const float*)d_in[7];
  float* out = (float*)d_out;

  // workspace layout (fp16 elems): xb 8M | wb 3M | owb 1M | qk 16M | vt 8M | ao 8M
  _Float16* xb = (_Float16*)d_ws;
  _Float16* wb = xb + (size_t)8388608;
  _Float16* owb = wb + (size_t)3145728;
  _Float16* qkbuf = owb + (size_t)1048576;
  _Float16* vtbuf = qkbuf + (size_t)16777216;
  _Float16* ao = vtbuf + (size_t)8388608;

  cvt_kernel<<<8192, 256, 0, stream>>>(x, xb, 2097152);
  cvt_kernel<<<2048, 256, 0, stream>>>(qk_w, wb, 524288);
  cvt_kernel<<<1024, 256, 0, stream>>>(v_w, wb + 2097152, 262144);
  cvt_kernel<<<1024, 256, 0, stream>>>(out_w, owb, 262144);

  // fused QKV projection: M=8192, N=3072 (2048 qk | 1024 v), K=1024
  gemm_kernel<0><<<dim3(24, 64), 256, 0, stream>>>(
      xb, wb, 8192, 3072, 1024, qk_b, v_b, qkbuf, vtbuf, nullptr, nullptr);

  // flash attention: B*H*(L/64) blocks
  attn_kernel<<<2048, 256, 0, stream>>>(qkbuf, vtbuf, bias, ao);

  // output projection: M=8192, N=1024, K=1024 -> fp32 d_out
  gemm_kernel<1><<<dim3(8, 64), 256, 0, stream>>>(
      ao, owb, 8192, 1024, 1024, nullptr, nullptr, nullptr, nullptr, out_b, out);
}

// Round 2
// 317.365 us; speedup vs baseline: 1.1676x; 1.1676x over previous
//
#include <hip/hip_runtime.h>
#include <cmath>

// ---------------------------------------------------------------------------
// T5 MHSA: x->(QKV proj, f16 MFMA GEMM) -> flash attn w/ T5 bias -> out proj
// All matmuls on MFMA. fp16 intermediates, fp32 accum.
// ---------------------------------------------------------------------------

typedef _Float16 f16x8 __attribute__((ext_vector_type(8)));
typedef _Float16 f16x4 __attribute__((ext_vector_type(4)));
typedef float    f32x4 __attribute__((ext_vector_type(4)));

#define NEG_INF (-__builtin_inff())
#define LOG2E 1.4426950408889634f

__device__ __forceinline__ void gl_lds16(const void* g, void* l) {
  __builtin_amdgcn_global_load_lds(
      (__attribute__((address_space(1))) void*)g,
      (__attribute__((address_space(3))) void*)l,
      16, 0, 0);
}

__device__ __forceinline__ f32x4 mfma32(f16x8 a, f16x8 b, f32x4 c) {
  return __builtin_amdgcn_mfma_f32_16x16x32_f16(a, b, c, 0, 0, 0);
}
__device__ __forceinline__ f32x4 mfma16(f16x4 a, f16x4 b, f32x4 c) {
  return __builtin_amdgcn_mfma_f32_16x16x16f16(a, b, c, 0, 0, 0);
}

// -------------------------------- convert ---------------------------------
__global__ void cvt_kernel(const float* __restrict__ in,
                           _Float16* __restrict__ out, int n4) {
  int i = blockIdx.x * blockDim.x + threadIdx.x;
  if (i >= n4) return;
  float4 v = reinterpret_cast<const float4*>(in)[i];
  f16x4 o;
  o[0] = (_Float16)v.x; o[1] = (_Float16)v.y;
  o[2] = (_Float16)v.z; o[3] = (_Float16)v.w;
  reinterpret_cast<f16x4*>(out)[i] = o;
}

// --------------------------------- GEMM -----------------------------------
// C = A(MxK) * Bm(NxK)^T.  128x128 tile, BK=32, 4 waves (2x2 of 64x64).
template <int MODE>
__global__ __launch_bounds__(256, 2) void gemm_kernel(
    const _Float16* __restrict__ A, const _Float16* __restrict__ Bm,
    int M, int N, int K,
    const float* __restrict__ bias_q, const float* __restrict__ bias_v,
    _Float16* __restrict__ qkbuf, _Float16* __restrict__ vtbuf,
    const float* __restrict__ bias_o, float* __restrict__ outf) {
  __shared__ __align__(16) _Float16 lds_a[128 * 32];
  __shared__ __align__(16) _Float16 lds_b[128 * 32];
  const int t = threadIdx.x;
  const int w = t >> 6;
  const int lane = t & 63;
  const int lq = lane & 15, lg = lane >> 4;
  const int wr = w >> 1, wc = w & 1;
  const int m0 = blockIdx.y * 128, n0 = blockIdx.x * 128;

  const _Float16* pA0 = A + (size_t)(m0 + (t >> 2)) * K + (t & 3) * 8;
  const _Float16* pA1 = pA0 + (size_t)64 * K;
  const _Float16* pB0 = Bm + (size_t)(n0 + (t >> 2)) * K + (t & 3) * 8;
  const _Float16* pB1 = pB0 + (size_t)64 * K;
  _Float16* la0 = &lds_a[(w * 64) * 8];
  _Float16* la1 = &lds_a[(256 + w * 64) * 8];
  _Float16* lb0 = &lds_b[(w * 64) * 8];
  _Float16* lb1 = &lds_b[(256 + w * 64) * 8];

  f32x4 acc[4][4];
#pragma unroll
  for (int mi = 0; mi < 4; ++mi)
#pragma unroll
    for (int ni = 0; ni < 4; ++ni) acc[mi][ni] = (f32x4){0.f, 0.f, 0.f, 0.f};

  for (int k0 = 0; k0 < K; k0 += 32) {
    __syncthreads();
    gl_lds16(pA0 + k0, la0);
    gl_lds16(pA1 + k0, la1);
    gl_lds16(pB0 + k0, lb0);
    gl_lds16(pB1 + k0, lb1);
    __syncthreads();
    f16x8 af[4], bfr[4];
#pragma unroll
    for (int mi = 0; mi < 4; ++mi)
      af[mi] = *(const f16x8*)&lds_a[(wr * 64 + mi * 16 + lq) * 32 + lg * 8];
#pragma unroll
    for (int ni = 0; ni < 4; ++ni)
      bfr[ni] = *(const f16x8*)&lds_b[(wc * 64 + ni * 16 + lq) * 32 + lg * 8];
#pragma unroll
    for (int mi = 0; mi < 4; ++mi)
#pragma unroll
      for (int ni = 0; ni < 4; ++ni)
        acc[mi][ni] = mfma32(af[mi], bfr[ni], acc[mi][ni]);
  }

  if (MODE == 0) {
    const bool isqk = (n0 < 2048);
#pragma unroll
    for (int mi = 0; mi < 4; ++mi)
#pragma unroll
      for (int ni = 0; ni < 4; ++ni)
#pragma unroll
        for (int r = 0; r < 4; ++r) {
          const int mg = m0 + wr * 64 + mi * 16 + lg * 4 + r;
          const int ng = n0 + wc * 64 + ni * 16 + lq;
          const int bb = mg >> 10, ii = mg & 1023;
          float val = acc[mi][ni][r];
          if (isqk) {
            val += bias_q[ng];
            const int hh = ng >> 7, cc = ng & 127;
            qkbuf[((size_t)((bb * 16 + hh) * 1024 + ii)) * 128 + cc] =
                (_Float16)val;
          } else {
            const int nn = ng - 2048;
            val += bias_v[nn];
            const int hh = nn >> 6, dv = nn & 63;
            vtbuf[((size_t)((bb * 16 + hh) * 64 + dv)) * 1024 + ii] =
                (_Float16)val;
          }
        }
  } else {
#pragma unroll
    for (int mi = 0; mi < 4; ++mi)
#pragma unroll
      for (int ni = 0; ni < 4; ++ni)
#pragma unroll
        for (int r = 0; r < 4; ++r) {
          const int mg = m0 + wr * 64 + mi * 16 + lg * 4 + r;
          const int ng = n0 + wc * 64 + ni * 16 + lq;
          outf[(size_t)mg * N + ng] = acc[mi][ni][r] + bias_o[ng];
        }
  }
}

// ------------------------------- attention --------------------------------
// Block = 4 waves, 256 thr. Each wave owns TWO 16-row q-subtiles of one
// (b,h): s (early, short j-range) and 63-s (late, long j-range) so per-wave
// work is constant (causal balance). K/V fragments are loaded once per
// j-tile and shared by both q-sets.
// S^T = mfma_16x16x32(K,Q): lane holds S[q=lq][j=j0+lg*4+r]. This IS the
// A-fragment layout of mfma_f32_16x16x16f16, so PV needs no repack at all.
__device__ __forceinline__ void attn_tile(
    const f16x8& qf0, const f16x8& qf1, const f16x8& kf0, const f16x8& kf1,
    const f16x8& kf2, const f16x8& kf3, const f16x4 (&vf)[4][2],
    const float* __restrict__ tab, int qi, int j0, int lg4, float& m_run,
    float& l_run, f32x4 (&oacc)[4]) {
  f32x4 st0 = {0.f, 0.f, 0.f, 0.f}, st1 = {0.f, 0.f, 0.f, 0.f};
  st0 = mfma32(kf0, qf0, st0);
  st0 = mfma32(kf1, qf1, st0);
  st1 = mfma32(kf2, qf0, st1);
  st1 = mfma32(kf3, qf1, st1);
  float xs[8];
  float tmax = NEG_INF;
#pragma unroll
  for (int hh = 0; hh < 2; ++hh)
#pragma unroll
    for (int r = 0; r < 4; ++r) {
      const int jj = j0 + hh * 16 + lg4 + r;
      const int dd = qi - jj;
      const float sv = hh ? st1[r] : st0[r];
      // scores pre-scaled by log2e (tab already has log2e folded in)
      const float xv =
          (dd < 0) ? NEG_INF
                   : fmaf(sv, 0.125f * LOG2E, tab[dd > 128 ? 128 : dd]);
      xs[hh * 4 + r] = xv;
      tmax = fmaxf(tmax, xv);
    }
  tmax = fmaxf(tmax, __shfl_xor(tmax, 16));
  tmax = fmaxf(tmax, __shfl_xor(tmax, 32));
  const float m_new = fmaxf(m_run, tmax);
  const float sf = exp2f(m_run - m_new);
  m_run = m_new;
  float p[8];
  float tsum = 0.f;
#pragma unroll
  for (int e = 0; e < 8; ++e) {
    p[e] = exp2f(xs[e] - m_new);
    tsum += p[e];
  }
  tsum += __shfl_xor(tsum, 16);
  tsum += __shfl_xor(tsum, 32);
  l_run = l_run * sf + tsum;
  // rescale O: oacc element r is q-row lg4+r; stats live at lanes 0..15
  f32x4 sfv;
#pragma unroll
  for (int r = 0; r < 4; ++r) sfv[r] = __shfl(sf, lg4 + r);
#pragma unroll
  for (int db = 0; db < 4; ++db) oacc[db] *= sfv;
  f16x4 ph0, ph1;
#pragma unroll
  for (int r = 0; r < 4; ++r) {
    ph0[r] = (_Float16)p[r];
    ph1[r] = (_Float16)p[4 + r];
  }
#pragma unroll
  for (int db = 0; db < 4; ++db) {
    oacc[db] = mfma16(ph0, vf[db][0], oacc[db]);
    oacc[db] = mfma16(ph1, vf[db][1], oacc[db]);
  }
}

__global__ __launch_bounds__(256, 4) void attn_kernel(
    const _Float16* __restrict__ qk,  // [B*H][1024][128] (q | k)
    const _Float16* __restrict__ vt,  // [B*H][64][1024]  (V^T)
    const float* __restrict__ bias,   // [32][16]
    _Float16* __restrict__ ao) {      // [B][1024][H*64]
  __shared__ float tab[132];
  const int t = threadIdx.x;
  const int bid = blockIdx.x;
  // XCD swizzle: the 8 blocks of one (b,h) share bid%8 -> same XCD's L2
  const int bh = (bid & 7) * 16 + (bid >> 6);
  const int b4 = (bid >> 3) & 7;
  const int h = bh & 15, b = bh >> 4;
  if (t < 129) {
    const int bucket =
        (t <= 16) ? t : 16 + (int)(log((double)(t - 15)) * 15.0 / log(113.0));
    tab[t] = bias[bucket * 16 + h] * LOG2E;
  }
  __syncthreads();

  const int w = t >> 6, lane = t & 63;
  const int lq = lane & 15, lg = lane >> 4;
  const int lg4 = lg * 4;
  const int sA = b4 * 4 + w;   // [0,32)
  const int sB = 63 - sA;      // [32,64)
  const int q0A = sA * 16, q0B = sB * 16;
  const int qA = q0A + lq, qB = q0B + lq;
  const _Float16* qkb = qk + (size_t)bh * 1024 * 128;
  const _Float16* kb = qkb + 64;
  const _Float16* vtb = vt + (size_t)bh * 64 * 1024;

  const f16x8 qfA0 = *(const f16x8*)&qkb[qA * 128 + lg * 8];
  const f16x8 qfA1 = *(const f16x8*)&qkb[qA * 128 + 32 + lg * 8];
  const f16x8 qfB0 = *(const f16x8*)&qkb[qB * 128 + lg * 8];
  const f16x8 qfB1 = *(const f16x8*)&qkb[qB * 128 + 32 + lg * 8];

  f32x4 oA[4], oB[4];
#pragma unroll
  for (int db = 0; db < 4; ++db) {
    oA[db] = (f32x4){0.f, 0.f, 0.f, 0.f};
    oB[db] = (f32x4){0.f, 0.f, 0.f, 0.f};
  }
  float mA = NEG_INF, lA = 0.f, mB = NEG_INF, lB = 0.f;
  const int njtA = (q0A + 47) >> 5;
  const int njtB = (q0B + 47) >> 5;

  for (int jt = 0; jt < njtB; ++jt) {
    const int j0 = jt * 32;
    const f16x8 kf0 = *(const f16x8*)&kb[(size_t)(j0 + lq) * 128 + lg * 8];
    const f16x8 kf1 = *(const f16x8*)&kb[(size_t)(j0 + lq) * 128 + 32 + lg * 8];
    const f16x8 kf2 = *(const f16x8*)&kb[(size_t)(j0 + 16 + lq) * 128 + lg * 8];
    const f16x8 kf3 =
        *(const f16x8*)&kb[(size_t)(j0 + 16 + lq) * 128 + 32 + lg * 8];
    f16x4 vf[4][2];
#pragma unroll
    for (int db = 0; db < 4; ++db) {
      vf[db][0] = *(const f16x4*)&vtb[(size_t)(db * 16 + lq) * 1024 + j0 + lg4];
      vf[db][1] =
          *(const f16x4*)&vtb[(size_t)(db * 16 + lq) * 1024 + j0 + 16 + lg4];
    }
    if (jt < njtA)
      attn_tile(qfA0, qfA1, kf0, kf1, kf2, kf3, vf, tab, qA, j0, lg4, mA, lA,
                oA);
    attn_tile(qfB0, qfB1, kf0, kf1, kf2, kf3, vf, tab, qB, j0, lg4, mB, lB,
              oB);
  }

  _Float16* aob = ao + ((size_t)b * 1024) * 1024 + h * 64;
  {
    f32x4 linv;
#pragma unroll
    for (int r = 0; r < 4; ++r) linv[r] = 1.0f / __shfl(lA, lg4 + r);
#pragma unroll
    for (int db = 0; db < 4; ++db)
#pragma unroll
      for (int r = 0; r < 4; ++r)
        aob[(size_t)(q0A + lg4 + r) * 1024 + db * 16 + lq] =
            (_Float16)(oA[db][r] * linv[r]);
  }
  {
    f32x4 linv;
#pragma unroll
    for (int r = 0; r < 4; ++r) linv[r] = 1.0f / __shfl(lB, lg4 + r);
#pragma unroll
    for (int db = 0; db < 4; ++db)
#pragma unroll
      for (int r = 0; r < 4; ++r)
        aob[(size_t)(q0B + lg4 + r) * 1024 + db * 16 + lq] =
            (_Float16)(oB[db][r] * linv[r]);
  }
}

// -------------------------------- launch ----------------------------------
extern "C" void kernel_launch(void* const* d_in, const int* in_sizes, int n_in,
                              void* d_out, int out_size, void* d_ws,
                              size_t ws_size, hipStream_t stream) {
  const float* x = (const float*)d_in[0];
  const float* qk_w = (const float*)d_in[1];
  const float* qk_b = (const float*)d_in[2];
  const float* v_w = (const float*)d_in[3];
  const float* v_b = (const float*)d_in[4];
  const float* out_w = (const float*)d_in[5];
  const float* out_b = (const float*)d_in[6];
  const float* bias = (const float*)d_in[7];
  float* out = (float*)d_out;

  // workspace (fp16 elems): xb 8M | wb 3M | owb 1M | qk 16M | vt 8M | ao 8M
  _Float16* xb = (_Float16*)d_ws;
  _Float16* wb = xb + (size_t)8388608;
  _Float16* owb = wb + (size_t)3145728;
  _Float16* qkbuf = owb + (size_t)1048576;
  _Float16* vtbuf = qkbuf + (size_t)16777216;
  _Float16* ao = vtbuf + (size_t)8388608;

  cvt_kernel<<<8192, 256, 0, stream>>>(x, xb, 2097152);
  cvt_kernel<<<2048, 256, 0, stream>>>(qk_w, wb, 524288);
  cvt_kernel<<<1024, 256, 0, stream>>>(v_w, wb + 2097152, 262144);
  cvt_kernel<<<1024, 256, 0, stream>>>(out_w, owb, 262144);

  // fused QKV projection: M=8192, N=3072 (2048 qk | 1024 v), K=1024
  gemm_kernel<0><<<dim3(24, 64), 256, 0, stream>>>(
      xb, wb, 8192, 3072, 1024, qk_b, v_b, qkbuf, vtbuf, nullptr, nullptr);

  // flash attention: B*H*8 balanced blocks
  attn_kernel<<<1024, 256, 0, stream>>>(qkbuf, vtbuf, bias, ao);

  // output projection: M=8192, N=1024, K=1024 -> fp32 d_out
  gemm_kernel<1><<<dim3(8, 64), 256, 0, stream>>>(
      ao, owb, 8192, 1024, 1024, nullptr, nullptr, nullptr, nullptr, out_b, out);
}